// Round 7
// baseline (172.175 us; speedup 1.0000x reference)
//
#include <hip/hip_runtime.h>
#include <stdint.h>

#define BB 8
#define NN 50000
#define SCORE_THR 0.99f
#define NMS_THR 0.5f
#define MAX_DET 100
#define K_PRE 1024
#define CAP 2048
#define KEEP_CAP 128
#define NBLK 196           // ceil(50000/256) filter blocks per batch
#define SLOT_MAX 32        // max candidates per (filter-block, class); P(exceed) ~ 1e-30
#define T_MAX 16           // K_PRE / 64
#define TRI_WORDS 8704     // 64 * T_MAX*(T_MAX+1)/2 u64 words per (b,c)

typedef unsigned long long u64;
typedef unsigned int u32;
typedef __attribute__((ext_vector_type(2))) unsigned long long u64x2;

// ws layout (bytes):
//   int blkcnt[64][NBLK]            @ 0          (50176; written unconditionally each launch)
//   u64 cand_blk[64][NBLK][SLOT_MAX]@ 51200      (3.2 MB, sparse)
//   u64 rowmask[64][TRI_WORDS]      @ 3262464    (4.25 MB triangular bit-matrix, L2-resident)
//   u64 kept_keys[64][KEEP_CAP]     @ 7718912    (64 KB)
//   int kept_cnt[64]                @ 7784448

// ---- D1: filter + per-block deterministic compaction (no atomics, no init) ----
__global__ __launch_bounds__(256) void k_filter(const float* __restrict__ cls,
                                                int* __restrict__ blkcnt,
                                                u64* __restrict__ cand_blk) {
    __shared__ int wcnt[8][4];
    __shared__ int woff[8][4];
    int gx = blockIdx.x;
    int b = blockIdx.y;
    int tid = threadIdx.x;
    int lane = tid & 63, w = tid >> 6;
    int n = gx * 256 + tid;
    bool vn = n < NN;
    float s[8];
    if (vn) {
        const float4* p = (const float4*)(cls + ((size_t)b * NN + n) * 8);
        float4 a = p[0], b2 = p[1];
        s[0] = a.x; s[1] = a.y; s[2] = a.z; s[3] = a.w;
        s[4] = b2.x; s[5] = b2.y; s[6] = b2.z; s[7] = b2.w;
    } else {
        #pragma unroll
        for (int c = 0; c < 8; ++c) s[c] = 0.f;
    }
    u64 bal[8];
    #pragma unroll
    for (int c = 0; c < 8; ++c) {
        bool pred = vn && (s[c] > SCORE_THR);
        bal[c] = __ballot(pred);
        if (lane == 0) wcnt[c][w] = (int)__popcll(bal[c]);
    }
    __syncthreads();
    if (tid < 8) {
        int c = tid, acc = 0;
        #pragma unroll
        for (int ww = 0; ww < 4; ++ww) { woff[c][ww] = acc; acc += wcnt[c][ww]; }
        blkcnt[(b * 8 + c) * NBLK + gx] = acc < SLOT_MAX ? acc : SLOT_MAX;
    }
    __syncthreads();
    #pragma unroll
    for (int c = 0; c < 8; ++c) {
        if (vn && (s[c] > SCORE_THR)) {
            int slot = woff[c][w] + (int)__popcll(bal[c] & ((1ull << lane) - 1ull));
            if (slot < SLOT_MAX)
                cand_blk[((size_t)(b * 8 + c) * NBLK + gx) * SLOT_MAX + slot] =
                    ((u64)__float_as_uint(s[c]) << 32) | (u32)(~(u32)n);
        }
    }
}

// ---- D2: per-(b,c) block: gather -> rank-sort -> IoU bit-matrix -> greedy ----
__global__ __launch_bounds__(1024) void k_nmsall(const float* __restrict__ boxes,
                                                 const int* __restrict__ blkcnt,
                                                 const u64* __restrict__ cand_blk,
                                                 u64* __restrict__ rowmask,
                                                 int* __restrict__ kept_cnt,
                                                 u64* __restrict__ kept_keys) {
    __shared__ __align__(16) u64 skin[CAP];     // 16 KB raw keys
    __shared__ u64 sk[K_PRE];                   // 8 KB sorted keys
    __shared__ float4 box4L[K_PRE];             // 16 KB sorted boxes
    __shared__ float areaL[K_PRE];              // 4 KB areas
    __shared__ int scntb[NBLK];
    __shared__ int pref[NBLK];
    __shared__ int cntTotS;
    int tid = threadIdx.x;
    int lane = tid & 63, w = tid >> 6;
    int bc = blockIdx.x;
    int c = bc & 7;
    int b = bc >> 3;
    // A: load per-filter-block counts
    if (tid < NBLK) scntb[tid] = blkcnt[bc * NBLK + tid];
    __syncthreads();
    // B: wave-0 exclusive prefix scan of 196 counts
    if (w == 0) {
        int carry = 0;
        #pragma unroll
        for (int r = 0; r < 4; ++r) {
            int idx = r * 64 + lane;
            int v = (idx < NBLK) ? scntb[idx] : 0;
            int x = v;
            #pragma unroll
            for (int d = 1; d < 64; d <<= 1) {
                int t = __shfl_up(x, d);
                if (lane >= d) x += t;
            }
            if (idx < NBLK) pref[idx] = carry + x - v;
            carry += __shfl(x, 63);
        }
        if (lane == 0) cntTotS = carry;
    }
    __syncthreads();
    int cnt = cntTotS;
    if (cnt > CAP) cnt = CAP;
    // C: gather candidates into contiguous LDS (4 threads per filter-block)
    if (tid < NBLK * 4) {
        int blk = tid >> 2, part = tid & 3;
        int cb = scntb[blk];
        int base = pref[blk];
        int k0 = part * 8, k1 = k0 + 8; if (k1 > cb) k1 = cb;
        const u64* src = cand_blk + ((size_t)bc * NBLK + blk) * SLOT_MAX;
        for (int k = k0; k < k1; ++k) {
            int dst = base + k;
            if (dst < CAP) skin[dst] = src[k];
        }
    }
    __syncthreads();
    if (tid == 0 && (cnt & 1)) skin[cnt] = 0ull;   // even-pad for paired reads
    __syncthreads();
    // C2: rank sort (keys globally distinct => exact permutation), gather boxes
    int cnt2 = (cnt + 1) & ~1;
    int nv = cnt2 >> 1;
    const u64x2* skv = (const u64x2*)skin;
    for (int g = 0; g < cnt; g += 1024) {
        int i0 = g + tid;
        u64 k0 = (i0 < cnt) ? skin[i0] : 0ull;
        int r0 = 0;
        #pragma unroll 4
        for (int jv = 0; jv < nv; ++jv) {
            u64x2 kk = skv[jv];
            r0 += (kk.x > k0); r0 += (kk.y > k0);
        }
        if (i0 < cnt && r0 < K_PRE) {
            sk[r0] = k0;
            u32 n = ~(u32)k0;
            float4 b4 = *(const float4*)(boxes + ((size_t)b * NN + n) * 4);
            box4L[r0] = b4;
            areaL[r0] = (b4.z - b4.x) * (b4.w - b4.y);
        }
    }
    __syncthreads();
    int n_cand = cnt < K_PRE ? cnt : K_PRE;
    int ntiles = (n_cand + 63) >> 6;
    int npairs = ntiles * (ntiles + 1) / 2;
    // D: triangular IoU bit matrix -> global rowmask (same layout as proven k_iou)
    {
        int tg = tid >> 8;            // 4 groups of 4 waves
        int sub = (tid >> 6) & 3;     // wave-in-group
        u64* rm = rowmask + (size_t)bc * TRI_WORDS;
        for (int p = tg; p < npairs; p += 4) {
            int ti = 0, acc = 0;
            while (acc + ti + 1 <= p) { acc += ti + 1; ++ti; }
            int tj = p - acc;
            int cg = tj * 64 + lane;
            float4 cb = box4L[cg];
            float ca = areaL[cg];
            u64* outw = rm + 64 * (ti * (ti + 1) / 2) + tj;
            #pragma unroll
            for (int r16 = 0; r16 < 16; ++r16) {
                int r = (sub << 4) | r16;
                float4 rb = box4L[ti * 64 + r];
                float ra = areaL[ti * 64 + r];
                float iw = fminf(rb.z, cb.z) - fmaxf(rb.x, cb.x);
                float ih = fminf(rb.w, cb.w) - fmaxf(rb.y, cb.y);
                iw = fmaxf(iw, 0.f); ih = fmaxf(ih, 0.f);
                float inter = iw * ih;
                float iou = inter / (ra + ca - inter);
                int rg = ti * 64 + r;
                bool pr = (rg < n_cand) && (cg < n_cand) && ((ti != tj) || (lane < r)) &&
                          (iou > NMS_THR);
                u64 m = __ballot(pr);
                if (lane == 0) outw[(size_t)r * (ti + 1)] = m;
            }
        }
    }
    __syncthreads();
    // E: wave-0 greedy over bit matrix (proven alive-mask scan), emit kept keys
    if (w == 0) {
        const u64* tri = rowmask + (size_t)bc * TRI_WORDS;
        u64 kept_w[T_MAX];
        #pragma unroll
        for (int t = 0; t < T_MAX; ++t) kept_w[t] = 0ull;
        for (int t = 0; t < ntiles; ++t) {
            const u64* base = tri + 64 * (t * (t + 1) / 2) + (size_t)lane * (t + 1);
            u64 supbits = 0;
            #pragma unroll
            for (int ww = 0; ww < T_MAX - 1; ++ww)
                if (ww < t) supbits |= base[ww] & kept_w[ww];
            u64 rowm = base[t];
            int g = t * 64 + lane;
            bool el = (g < n_cand) && (supbits == 0ull);
            u64 alive = __ballot(el);
            u64 kb = 0;
            while (alive) {
                int j = __ffsll(alive) - 1;
                kb |= (1ull << j);
                u64 colj = __ballot(((rowm >> j) & 1ull) != 0);
                alive &= ~(colj | (1ull << j));
            }
            #pragma unroll
            for (int ww = 0; ww < T_MAX; ++ww)
                if (ww == t) kept_w[ww] = kb;
        }
        u64 lmask = (1ull << lane) - 1ull;
        int pre = 0;
        #pragma unroll
        for (int t = 0; t < T_MAX; ++t) {
            if (t < ntiles) {
                u64 kb = kept_w[t];
                if ((kb >> lane) & 1ull) {
                    int rank = pre + (int)__popcll(kb & lmask);
                    if (rank < KEEP_CAP) {
                        int i = t * 64 + lane;
                        u64 key = sk[i];
                        u32 sb = (u32)(key >> 32);
                        u32 n = (~(u32)key) & 0x1FFFFu;
                        int pos = c * K_PRE + i;
                        kept_keys[(size_t)bc * KEEP_CAP + rank] =
                            ((u64)sb << 30) | ((u64)(8191 - pos) << 17) | (u64)n;
                    }
                }
                pre += (int)__popcll(kb);
            }
        }
        if (lane == 0) kept_cnt[bc] = pre < KEEP_CAP ? pre : KEEP_CAP;
    }
}

// ---- D3: top-100 via per-run binary search (verbatim from proven round 5) ----
__global__ __launch_bounds__(1024) void k_final(const float* __restrict__ boxes,
                                                const float* __restrict__ rot,
                                                const float* __restrict__ trans,
                                                const int* __restrict__ kept_cnt,
                                                const u64* __restrict__ kept_keys,
                                                float* __restrict__ out) {
    __shared__ u64 fk[1024];      // 8 strictly-descending runs of 128 (0-padded)
    __shared__ int scnt[8];
    int tid = threadIdx.x;
    int b = blockIdx.x;
    int c = tid >> 7, i = tid & 127;
    if (tid < 8) scnt[tid] = kept_cnt[b * 8 + tid];
    int cc = kept_cnt[b * 8 + c];
    u64 key = (i < cc) ? kept_keys[(size_t)(b * 8 + c) * KEEP_CAP + i] : 0ull;
    fk[tid] = key;
    __syncthreads();
    int total = 0;
    #pragma unroll
    for (int r = 0; r < 8; ++r) total += scnt[r];
    if (i < cc) {
        int rank = i;
        #pragma unroll
        for (int r = 0; r < 8; ++r) {
            if (r == c) continue;
            int basei = r << 7;
            int lo;
            if (fk[basei + 127] > key) lo = 128;
            else {
                lo = 0;
                #pragma unroll
                for (int s = 64; s > 0; s >>= 1)
                    if (fk[basei + lo + s - 1] > key) lo += s;
            }
            rank += lo;
        }
        if (rank < MAX_DET) {
            u32 n = (u32)(key & 0x1FFFFu);
            int pos = 8191 - (int)((key >> 17) & 0x1FFFu);
            int cls = pos >> 10;
            float osc = __uint_as_float((u32)(key >> 30));
            const float* bp = boxes + ((size_t)b * NN + n) * 4;
            const float* rp = rot + ((size_t)b * NN + n) * 3;
            const float* tp = trans + ((size_t)b * NN + n) * 3;
            int base = b * MAX_DET + rank;
            out[base * 4 + 0] = bp[0];
            out[base * 4 + 1] = bp[1];
            out[base * 4 + 2] = bp[2];
            out[base * 4 + 3] = bp[3];
            out[BB * MAX_DET * 4 + base] = osc;
            out[BB * MAX_DET * 5 + base] = (float)cls;
            float* ro = out + BB * MAX_DET * 6;
            ro[base * 3 + 0] = rp[0];
            ro[base * 3 + 1] = rp[1];
            ro[base * 3 + 2] = rp[2];
            float* to = out + BB * MAX_DET * 6 + BB * MAX_DET * 3;
            to[base * 3 + 0] = tp[0];
            to[base * 3 + 1] = tp[1];
            to[base * 3 + 2] = tp[2];
        }
    }
    if (tid < MAX_DET && tid >= total) {
        int base = b * MAX_DET + tid;
        out[base * 4 + 0] = -1.f;
        out[base * 4 + 1] = -1.f;
        out[base * 4 + 2] = -1.f;
        out[base * 4 + 3] = -1.f;
        out[BB * MAX_DET * 4 + base] = -1.f;
        out[BB * MAX_DET * 5 + base] = -1.f;
        float* ro = out + BB * MAX_DET * 6;
        ro[base * 3 + 0] = -1.f;
        ro[base * 3 + 1] = -1.f;
        ro[base * 3 + 2] = -1.f;
        float* to = out + BB * MAX_DET * 6 + BB * MAX_DET * 3;
        to[base * 3 + 0] = -1.f;
        to[base * 3 + 1] = -1.f;
        to[base * 3 + 2] = -1.f;
    }
}

extern "C" void kernel_launch(void* const* d_in, const int* in_sizes, int n_in,
                              void* d_out, int out_size, void* d_ws, size_t ws_size,
                              hipStream_t stream) {
    const float* boxes = (const float*)d_in[0];
    const float* cls   = (const float*)d_in[1];
    const float* rot   = (const float*)d_in[2];
    const float* trans = (const float*)d_in[3];
    char* ws = (char*)d_ws;
    int* blkcnt    = (int*)ws;                    // 50176 B
    u64* cand_blk  = (u64*)(ws + 51200);          // 3.2 MB
    u64* rowmask   = (u64*)(ws + 3262464);        // 4.25 MB
    u64* kept_keys = (u64*)(ws + 7718912);        // 64 KB
    int* kept_cnt  = (int*)(ws + 7784448);
    float* out = (float*)d_out;

    hipLaunchKernelGGL(k_filter, dim3(NBLK, BB), dim3(256), 0, stream,
                       cls, blkcnt, cand_blk);
    hipLaunchKernelGGL(k_nmsall, dim3(64), dim3(1024), 0, stream,
                       boxes, blkcnt, cand_blk, rowmask, kept_cnt, kept_keys);
    hipLaunchKernelGGL(k_final, dim3(BB), dim3(1024), 0, stream,
                       boxes, rot, trans, kept_cnt, kept_keys, out);
}

// Round 8
// 131.793 us; speedup vs baseline: 1.3064x; 1.3064x over previous
//
#include <hip/hip_runtime.h>
#include <stdint.h>

#define BB 8
#define NN 50000
#define SCORE_THR 0.99f
#define NMS_THR 0.5f
#define MAX_DET 100
#define K_PRE 1024
#define CAP 2048
#define KEEP_CAP 128
#define NBLK 196           // ceil(50000/256) filter blocks per batch
#define SLOT_MAX 32        // max candidates per (filter-block, class)
#define T_MAX 16           // K_PRE / 64
#define NPAIR 136          // T_MAX*(T_MAX+1)/2
#define TRI_WORDS 8704     // 64 * NPAIR u64 words per (b,c)
#define HB 2048            // score buckets

typedef unsigned long long u64;
typedef unsigned int u32;

// ws layout (bytes):
//   int    blkcnt[64][NBLK]             @ 0        (50176)
//   u64    cand_blk[64][NBLK][SLOT_MAX] @ 51200    (3.2 MB sparse)
//   int    cnt_g[64]                    @ 3262464
//   u64    sk_g[64][K_PRE]              @ 3262720  (512 KB)
//   float4 box4[64][K_PRE]              @ 3787008  (1 MB)
//   u64    rowmask[64][TRI_WORDS]       @ 4835584  (4.25 MB)

// ---- D1: filter + per-block deterministic compaction (proven R7) ----
__global__ __launch_bounds__(256) void k_filter(const float* __restrict__ cls,
                                                int* __restrict__ blkcnt,
                                                u64* __restrict__ cand_blk) {
    __shared__ int wcnt[8][4];
    __shared__ int woff[8][4];
    int gx = blockIdx.x;
    int b = blockIdx.y;
    int tid = threadIdx.x;
    int lane = tid & 63, w = tid >> 6;
    int n = gx * 256 + tid;
    bool vn = n < NN;
    float s[8];
    if (vn) {
        const float4* p = (const float4*)(cls + ((size_t)b * NN + n) * 8);
        float4 a = p[0], b2 = p[1];
        s[0] = a.x; s[1] = a.y; s[2] = a.z; s[3] = a.w;
        s[4] = b2.x; s[5] = b2.y; s[6] = b2.z; s[7] = b2.w;
    } else {
        #pragma unroll
        for (int c = 0; c < 8; ++c) s[c] = 0.f;
    }
    u64 bal[8];
    #pragma unroll
    for (int c = 0; c < 8; ++c) {
        bool pred = vn && (s[c] > SCORE_THR);
        bal[c] = __ballot(pred);
        if (lane == 0) wcnt[c][w] = (int)__popcll(bal[c]);
    }
    __syncthreads();
    if (tid < 8) {
        int c = tid, acc = 0;
        #pragma unroll
        for (int ww = 0; ww < 4; ++ww) { woff[c][ww] = acc; acc += wcnt[c][ww]; }
        blkcnt[(b * 8 + c) * NBLK + gx] = acc < SLOT_MAX ? acc : SLOT_MAX;
    }
    __syncthreads();
    #pragma unroll
    for (int c = 0; c < 8; ++c) {
        if (vn && (s[c] > SCORE_THR)) {
            int slot = woff[c][w] + (int)__popcll(bal[c] & ((1ull << lane) - 1ull));
            if (slot < SLOT_MAX)
                cand_blk[((size_t)(b * 8 + c) * NBLK + gx) * SLOT_MAX + slot] =
                    ((u64)__float_as_uint(s[c]) << 32) | (u32)(~(u32)n);
        }
    }
}

__device__ __forceinline__ int bucket_of(u64 key) {
    int bk = (int)(key >> 40) - 0x3F7D70;   // (score_bits>>8) - base; monotonic in key
    return bk < 0 ? 0 : (bk > HB - 1 ? HB - 1 : bk);
}

// ---- D2: per-(b,c) gather + O(n) bucket sort (exact: within-bucket full-key rank) ----
__global__ __launch_bounds__(256) void k_sortB(const float* __restrict__ boxes,
                                               const int* __restrict__ blkcnt,
                                               const u64* __restrict__ cand_blk,
                                               int* __restrict__ cnt_g,
                                               u64* __restrict__ sk_g,
                                               float4* __restrict__ box4) {
    __shared__ int scntb[NBLK];
    __shared__ int pref[NBLK];
    __shared__ int cntTotS;
    __shared__ __align__(16) u64 skin[CAP];
    __shared__ __align__(16) u64 tmp[CAP];
    __shared__ int hist[HB];
    __shared__ int pre[HB];
    __shared__ int offs[HB];
    __shared__ int wsumS[4];
    int tid = threadIdx.x;
    int lane = tid & 63, w = tid >> 6;
    int bc = blockIdx.x;
    int b = bc >> 3;
    if (tid < NBLK) scntb[tid] = blkcnt[bc * NBLK + tid];
    #pragma unroll
    for (int k = 0; k < HB / 256; ++k) hist[tid + 256 * k] = 0;
    __syncthreads();
    // exclusive prefix scan of 196 per-block counts (wave 0)
    if (w == 0) {
        int carry = 0;
        #pragma unroll
        for (int r = 0; r < 4; ++r) {
            int idx = r * 64 + lane;
            int v = (idx < NBLK) ? scntb[idx] : 0;
            int x = v;
            #pragma unroll
            for (int d = 1; d < 64; d <<= 1) {
                int t = __shfl_up(x, d);
                if (lane >= d) x += t;
            }
            if (idx < NBLK) pref[idx] = carry + x - v;
            carry += __shfl(x, 63);
        }
        if (lane == 0) cntTotS = carry;
    }
    __syncthreads();
    int cnt = cntTotS; if (cnt > CAP) cnt = CAP;
    // gather into contiguous LDS (one thread per filter-block)
    if (tid < NBLK) {
        int cb = scntb[tid], base = pref[tid];
        const u64* src = cand_blk + ((size_t)bc * NBLK + tid) * SLOT_MAX;
        for (int k = 0; k < cb; ++k) {
            int dst = base + k;
            if (dst < CAP) skin[dst] = src[k];
        }
    }
    __syncthreads();
    // histogram
    for (int i = tid; i < cnt; i += 256) atomicAdd(&hist[bucket_of(skin[i])], 1);
    __syncthreads();
    // prefix scan of HB buckets (ascending): 8/thread + wave scan + cross-wave
    int base8 = tid * (HB / 256);
    int loc[HB / 256];
    int s = 0;
    #pragma unroll
    for (int k = 0; k < HB / 256; ++k) { loc[k] = s; s += hist[base8 + k]; }
    int x = s;
    #pragma unroll
    for (int d = 1; d < 64; d <<= 1) {
        int t = __shfl_up(x, d);
        if (lane >= d) x += t;
    }
    if (lane == 63) wsumS[w] = x;
    __syncthreads();
    int wbase = 0;
    #pragma unroll
    for (int ww = 0; ww < 4; ++ww) if (ww < w) wbase += wsumS[ww];
    int tbase = wbase + x - s;
    #pragma unroll
    for (int k = 0; k < HB / 256; ++k) {
        pre[base8 + k] = tbase + loc[k];
        offs[base8 + k] = tbase + loc[k];
    }
    __syncthreads();
    // scatter (order within bucket nondeterministic; fixed next phase)
    for (int i = tid; i < cnt; i += 256) {
        u64 key = skin[i];
        int pos = atomicAdd(&offs[bucket_of(key)], 1);
        tmp[pos] = key;
    }
    __syncthreads();
    // exact descending position: keys-above-bucket + within-bucket strict-> rank
    for (int i = tid; i < cnt; i += 256) {
        u64 key = tmp[i];
        int bk = bucket_of(key);
        int s0 = pre[bk], len = hist[bk];
        int r = 0;
        for (int j = s0; j < s0 + len; ++j) r += (tmp[j] > key);
        int dst = (cnt - s0 - len) + r;     // descending overall
        skin[dst] = key;
    }
    __syncthreads();
    if (tid == 0) cnt_g[bc] = cnt;
    int n_cand = cnt < K_PRE ? cnt : K_PRE;
    for (int rr = tid; rr < n_cand; rr += 256) {
        u64 key = skin[rr];
        sk_g[(size_t)bc * K_PRE + rr] = key;
        u32 n = ~(u32)key;
        box4[(size_t)bc * K_PRE + rr] =
            *(const float4*)(boxes + ((size_t)b * NN + n) * 4);
    }
}

// ---- D3: triangular IoU bit matrix (proven R5, cnt source changed) ----
__global__ __launch_bounds__(256) void k_iou(const int* __restrict__ cnt_g,
                                             const float4* __restrict__ box4,
                                             u64* __restrict__ rowmask) {
    int bc = blockIdx.y;
    int p = blockIdx.x;
    int cnt = cnt_g[bc];
    int n_cand = cnt < K_PRE ? cnt : K_PRE;
    int ntiles = (n_cand + 63) >> 6;
    int ti = 0, acc = 0;
    while (acc + ti + 1 <= p) { acc += ti + 1; ++ti; }
    int tj = p - acc;
    if (ti >= ntiles) return;
    const float4* bx = box4 + (size_t)bc * K_PRE;
    __shared__ float4 srb[64];
    int tid = threadIdx.x;
    int lane = tid & 63, w = tid >> 6;
    if (tid < 64) srb[tid] = bx[ti * 64 + tid];
    __syncthreads();
    int cg = tj * 64 + lane;
    float4 cb = bx[cg];
    float ca = (cb.z - cb.x) * (cb.w - cb.y);
    u64* out = rowmask + (size_t)bc * TRI_WORDS + 64 * (ti * (ti + 1) / 2) + tj;
    #pragma unroll
    for (int r16 = 0; r16 < 16; ++r16) {
        int r = (w << 4) | r16;
        float4 rb = srb[r];
        float ra = (rb.z - rb.x) * (rb.w - rb.y);
        float iw = fminf(rb.z, cb.z) - fmaxf(rb.x, cb.x);
        float ih = fminf(rb.w, cb.w) - fmaxf(rb.y, cb.y);
        iw = fmaxf(iw, 0.f); ih = fmaxf(ih, 0.f);
        float inter = iw * ih;
        float iou = inter / (ra + ca - inter);
        int rg = ti * 64 + r;
        bool pr = (rg < n_cand) && (cg < n_cand) && ((ti != tj) || (lane < r)) &&
                  (iou > NMS_THR);
        u64 m = __ballot(pr);
        if (lane == 0) out[(size_t)r * (ti + 1)] = m;
    }
}

// ---- D4: fused greedy + top-100 (proven R6, cnt source changed) ----
__global__ __launch_bounds__(1024) void k_fuse(const float* __restrict__ boxes,
                                               const float* __restrict__ rot,
                                               const float* __restrict__ trans,
                                               const int* __restrict__ cnt_g,
                                               const u64* __restrict__ sk_g,
                                               const u64* __restrict__ rowmask,
                                               float* __restrict__ out) {
    __shared__ u64 fk[1024];
    __shared__ int scnt[8];
    int tid = threadIdx.x;
    int lane = tid & 63, w = tid >> 6;
    int b = blockIdx.x;
    fk[tid] = 0ull;
    __syncthreads();
    if (w < 8) {
        int c = w;
        int bc = b * 8 + c;
        int cnt = cnt_g[bc];
        int n_cand = cnt < K_PRE ? cnt : K_PRE;
        int ntiles = (n_cand + 63) >> 6;
        const u64* tri = rowmask + (size_t)bc * TRI_WORDS;
        u64 kept_w[T_MAX];
        #pragma unroll
        for (int t = 0; t < T_MAX; ++t) kept_w[t] = 0ull;
        for (int t = 0; t < ntiles; ++t) {
            const u64* base = tri + 64 * (t * (t + 1) / 2) + (size_t)lane * (t + 1);
            u64 supbits = 0;
            #pragma unroll
            for (int ww = 0; ww < T_MAX - 1; ++ww)
                if (ww < t) supbits |= base[ww] & kept_w[ww];
            u64 rowm = base[t];
            int g = t * 64 + lane;
            bool el = (g < n_cand) && (supbits == 0ull);
            u64 alive = __ballot(el);
            u64 kb = 0;
            while (alive) {
                int j = __ffsll(alive) - 1;
                kb |= (1ull << j);
                u64 colj = __ballot(((rowm >> j) & 1ull) != 0);
                alive &= ~(colj | (1ull << j));
            }
            #pragma unroll
            for (int ww = 0; ww < T_MAX; ++ww)
                if (ww == t) kept_w[ww] = kb;
        }
        u64 lmask = (1ull << lane) - 1ull;
        int pre = 0;
        #pragma unroll
        for (int t = 0; t < T_MAX; ++t) {
            if (t < ntiles) {
                u64 kb = kept_w[t];
                if ((kb >> lane) & 1ull) {
                    int rank = pre + (int)__popcll(kb & lmask);
                    if (rank < KEEP_CAP) {
                        int i = t * 64 + lane;
                        u64 key = sk_g[(size_t)bc * K_PRE + i];
                        u32 sb = (u32)(key >> 32);
                        u32 n = (~(u32)key) & 0x1FFFFu;
                        int pos = c * K_PRE + i;
                        fk[c * KEEP_CAP + rank] =
                            ((u64)sb << 30) | ((u64)(8191 - pos) << 17) | (u64)n;
                    }
                }
                pre += (int)__popcll(kb);
            }
        }
        if (lane == 0) scnt[c] = pre < KEEP_CAP ? pre : KEEP_CAP;
    }
    __syncthreads();
    int c = tid >> 7, i = tid & 127;
    int cc = scnt[c];
    u64 key = fk[tid];
    int total = 0;
    #pragma unroll
    for (int r = 0; r < 8; ++r) total += scnt[r];
    if (i < cc) {
        int rank = i;
        #pragma unroll
        for (int r = 0; r < 8; ++r) {
            if (r == c) continue;
            int basei = r << 7;
            int lo;
            if (fk[basei + 127] > key) lo = 128;
            else {
                lo = 0;
                #pragma unroll
                for (int s = 64; s > 0; s >>= 1)
                    if (fk[basei + lo + s - 1] > key) lo += s;
            }
            rank += lo;
        }
        if (rank < MAX_DET) {
            u32 n = (u32)(key & 0x1FFFFu);
            int pos = 8191 - (int)((key >> 17) & 0x1FFFu);
            int cls = pos >> 10;
            float osc = __uint_as_float((u32)(key >> 30));
            const float* bp = boxes + ((size_t)b * NN + n) * 4;
            const float* rp = rot + ((size_t)b * NN + n) * 3;
            const float* tp = trans + ((size_t)b * NN + n) * 3;
            int base = b * MAX_DET + rank;
            out[base * 4 + 0] = bp[0];
            out[base * 4 + 1] = bp[1];
            out[base * 4 + 2] = bp[2];
            out[base * 4 + 3] = bp[3];
            out[BB * MAX_DET * 4 + base] = osc;
            out[BB * MAX_DET * 5 + base] = (float)cls;
            float* ro = out + BB * MAX_DET * 6;
            ro[base * 3 + 0] = rp[0];
            ro[base * 3 + 1] = rp[1];
            ro[base * 3 + 2] = rp[2];
            float* to = out + BB * MAX_DET * 6 + BB * MAX_DET * 3;
            to[base * 3 + 0] = tp[0];
            to[base * 3 + 1] = tp[1];
            to[base * 3 + 2] = tp[2];
        }
    }
    if (tid < MAX_DET && tid >= total) {
        int base = b * MAX_DET + tid;
        out[base * 4 + 0] = -1.f;
        out[base * 4 + 1] = -1.f;
        out[base * 4 + 2] = -1.f;
        out[base * 4 + 3] = -1.f;
        out[BB * MAX_DET * 4 + base] = -1.f;
        out[BB * MAX_DET * 5 + base] = -1.f;
        float* ro = out + BB * MAX_DET * 6;
        ro[base * 3 + 0] = -1.f;
        ro[base * 3 + 1] = -1.f;
        ro[base * 3 + 2] = -1.f;
        float* to = out + BB * MAX_DET * 6 + BB * MAX_DET * 3;
        to[base * 3 + 0] = -1.f;
        to[base * 3 + 1] = -1.f;
        to[base * 3 + 2] = -1.f;
    }
}

extern "C" void kernel_launch(void* const* d_in, const int* in_sizes, int n_in,
                              void* d_out, int out_size, void* d_ws, size_t ws_size,
                              hipStream_t stream) {
    const float* boxes = (const float*)d_in[0];
    const float* cls   = (const float*)d_in[1];
    const float* rot   = (const float*)d_in[2];
    const float* trans = (const float*)d_in[3];
    char* ws = (char*)d_ws;
    int* blkcnt    = (int*)ws;
    u64* cand_blk  = (u64*)(ws + 51200);
    int* cnt_g     = (int*)(ws + 3262464);
    u64* sk_g      = (u64*)(ws + 3262720);
    float4* box4   = (float4*)(ws + 3787008);
    u64* rowmask   = (u64*)(ws + 4835584);
    float* out = (float*)d_out;

    hipLaunchKernelGGL(k_filter, dim3(NBLK, BB), dim3(256), 0, stream,
                       cls, blkcnt, cand_blk);
    hipLaunchKernelGGL(k_sortB, dim3(64), dim3(256), 0, stream,
                       boxes, blkcnt, cand_blk, cnt_g, sk_g, box4);
    hipLaunchKernelGGL(k_iou, dim3(NPAIR, 64), dim3(256), 0, stream,
                       cnt_g, box4, rowmask);
    hipLaunchKernelGGL(k_fuse, dim3(BB), dim3(1024), 0, stream,
                       boxes, rot, trans, cnt_g, sk_g, rowmask, out);
}

// Round 9
// 130.503 us; speedup vs baseline: 1.3193x; 1.0099x over previous
//
#include <hip/hip_runtime.h>
#include <stdint.h>

#define BB 8
#define NN 50000
#define SCORE_THR 0.99f
#define NMS_THR 0.5f
#define MAX_DET 100
#define K_PRE 1024
#define CAP 2048
#define KEEP_CAP 128
#define NBLK 196           // ceil(50000/256) filter blocks per batch
#define SLOT_MAX 32        // max candidates per (filter-block, class)
#define T_MAX 16           // K_PRE / 64
#define NPAIR 136          // T_MAX*(T_MAX+1)/2 (layout constant)
#define IOU_BLK 45         // launched pair-blocks per bc (grid-stride covers rest)
#define TRI_WORDS 8704     // 64 * NPAIR u64 words per (b,c)
#define HB 2048            // score buckets

typedef unsigned long long u64;
typedef unsigned int u32;

// ws layout (bytes):
//   int    blkcnt[64][NBLK]             @ 0        (50176)
//   u64    cand_blk[64][NBLK][SLOT_MAX] @ 51200    (3.2 MB sparse)
//   int    cnt_g[64]                    @ 3262464
//   u64    sk_g[64][K_PRE]              @ 3262720  (512 KB)
//   float4 box4[64][K_PRE]              @ 3787008  (1 MB)
//   u64    rowmask[64][TRI_WORDS]       @ 4835584  (4.25 MB)

// ---- D1: filter + per-block deterministic compaction (proven R7/R8) ----
__global__ __launch_bounds__(256) void k_filter(const float* __restrict__ cls,
                                                int* __restrict__ blkcnt,
                                                u64* __restrict__ cand_blk) {
    __shared__ int wcnt[8][4];
    __shared__ int woff[8][4];
    int gx = blockIdx.x;
    int b = blockIdx.y;
    int tid = threadIdx.x;
    int lane = tid & 63, w = tid >> 6;
    int n = gx * 256 + tid;
    bool vn = n < NN;
    float s[8];
    if (vn) {
        const float4* p = (const float4*)(cls + ((size_t)b * NN + n) * 8);
        float4 a = p[0], b2 = p[1];
        s[0] = a.x; s[1] = a.y; s[2] = a.z; s[3] = a.w;
        s[4] = b2.x; s[5] = b2.y; s[6] = b2.z; s[7] = b2.w;
    } else {
        #pragma unroll
        for (int c = 0; c < 8; ++c) s[c] = 0.f;
    }
    u64 bal[8];
    #pragma unroll
    for (int c = 0; c < 8; ++c) {
        bool pred = vn && (s[c] > SCORE_THR);
        bal[c] = __ballot(pred);
        if (lane == 0) wcnt[c][w] = (int)__popcll(bal[c]);
    }
    __syncthreads();
    if (tid < 8) {
        int c = tid, acc = 0;
        #pragma unroll
        for (int ww = 0; ww < 4; ++ww) { woff[c][ww] = acc; acc += wcnt[c][ww]; }
        blkcnt[(b * 8 + c) * NBLK + gx] = acc < SLOT_MAX ? acc : SLOT_MAX;
    }
    __syncthreads();
    #pragma unroll
    for (int c = 0; c < 8; ++c) {
        if (vn && (s[c] > SCORE_THR)) {
            int slot = woff[c][w] + (int)__popcll(bal[c] & ((1ull << lane) - 1ull));
            if (slot < SLOT_MAX)
                cand_blk[((size_t)(b * 8 + c) * NBLK + gx) * SLOT_MAX + slot] =
                    ((u64)__float_as_uint(s[c]) << 32) | (u32)(~(u32)n);
        }
    }
}

__device__ __forceinline__ int bucket_of(u64 key) {
    int bk = (int)(key >> 40) - 0x3F7D70;   // (score_bits>>8) - base; monotonic in key
    return bk < 0 ? 0 : (bk > HB - 1 ? HB - 1 : bk);
}

// ---- D2: per-(b,c) gather + O(n) bucket sort (exact within-bucket full-key rank) ----
__global__ __launch_bounds__(256) void k_sortB(const float* __restrict__ boxes,
                                               const int* __restrict__ blkcnt,
                                               const u64* __restrict__ cand_blk,
                                               int* __restrict__ cnt_g,
                                               u64* __restrict__ sk_g,
                                               float4* __restrict__ box4) {
    __shared__ int scntb[NBLK];
    __shared__ int pref[NBLK];
    __shared__ int cntTotS;
    __shared__ __align__(16) u64 skin[CAP];
    __shared__ __align__(16) u64 tmp[CAP];
    __shared__ int hist[HB];
    __shared__ int pre[HB];
    __shared__ int offs[HB];
    __shared__ int wsumS[4];
    int tid = threadIdx.x;
    int lane = tid & 63, w = tid >> 6;
    int bc = blockIdx.x;
    int b = bc >> 3;
    if (tid < NBLK) scntb[tid] = blkcnt[bc * NBLK + tid];
    #pragma unroll
    for (int k = 0; k < HB / 256; ++k) hist[tid + 256 * k] = 0;
    __syncthreads();
    // exclusive prefix scan of 196 per-block counts (wave 0)
    if (w == 0) {
        int carry = 0;
        #pragma unroll
        for (int r = 0; r < 4; ++r) {
            int idx = r * 64 + lane;
            int v = (idx < NBLK) ? scntb[idx] : 0;
            int x = v;
            #pragma unroll
            for (int d = 1; d < 64; d <<= 1) {
                int t = __shfl_up(x, d);
                if (lane >= d) x += t;
            }
            if (idx < NBLK) pref[idx] = carry + x - v;
            carry += __shfl(x, 63);
        }
        if (lane == 0) cntTotS = carry;
    }
    __syncthreads();
    int cnt = cntTotS; if (cnt > CAP) cnt = CAP;
    // gather into contiguous LDS + fused histogram (one thread per filter-block)
    if (tid < NBLK) {
        int cb = scntb[tid], base = pref[tid];
        const u64* src = cand_blk + ((size_t)bc * NBLK + tid) * SLOT_MAX;
        for (int k = 0; k < cb; ++k) {
            int dst = base + k;
            if (dst < CAP) {
                u64 key = src[k];
                skin[dst] = key;
                atomicAdd(&hist[bucket_of(key)], 1);
            }
        }
    }
    __syncthreads();
    // prefix scan of HB buckets (ascending): 8/thread + wave scan + cross-wave
    int base8 = tid * (HB / 256);
    int loc[HB / 256];
    int s = 0;
    #pragma unroll
    for (int k = 0; k < HB / 256; ++k) { loc[k] = s; s += hist[base8 + k]; }
    int x = s;
    #pragma unroll
    for (int d = 1; d < 64; d <<= 1) {
        int t = __shfl_up(x, d);
        if (lane >= d) x += t;
    }
    if (lane == 63) wsumS[w] = x;
    __syncthreads();
    int wbase = 0;
    #pragma unroll
    for (int ww = 0; ww < 4; ++ww) if (ww < w) wbase += wsumS[ww];
    int tbase = wbase + x - s;
    #pragma unroll
    for (int k = 0; k < HB / 256; ++k) {
        pre[base8 + k] = tbase + loc[k];
        offs[base8 + k] = tbase + loc[k];
    }
    __syncthreads();
    // scatter (order within bucket nondeterministic; fixed next phase)
    for (int i = tid; i < cnt; i += 256) {
        u64 key = skin[i];
        int pos = atomicAdd(&offs[bucket_of(key)], 1);
        tmp[pos] = key;
    }
    __syncthreads();
    // exact descending position: keys-above-bucket + within-bucket strict-> rank
    for (int i = tid; i < cnt; i += 256) {
        u64 key = tmp[i];
        int bk = bucket_of(key);
        int s0 = pre[bk], len = hist[bk];
        int r = 0;
        for (int j = s0; j < s0 + len; ++j) r += (tmp[j] > key);
        int dst = (cnt - s0 - len) + r;     // descending overall
        skin[dst] = key;
    }
    __syncthreads();
    if (tid == 0) cnt_g[bc] = cnt;
    int n_cand = cnt < K_PRE ? cnt : K_PRE;
    for (int rr = tid; rr < n_cand; rr += 256) {
        u64 key = skin[rr];
        sk_g[(size_t)bc * K_PRE + rr] = key;
        u32 n = ~(u32)key;
        box4[(size_t)bc * K_PRE + rr] =
            *(const float4*)(boxes + ((size_t)b * NN + n) * 4);
    }
}

// ---- D3: triangular IoU bit matrix (proven R5/R8; grid-stride over pairs) ----
__global__ __launch_bounds__(256) void k_iou(const int* __restrict__ cnt_g,
                                             const float4* __restrict__ box4,
                                             u64* __restrict__ rowmask) {
    int bc = blockIdx.y;
    int cnt = cnt_g[bc];
    int n_cand = cnt < K_PRE ? cnt : K_PRE;
    int ntiles = (n_cand + 63) >> 6;
    int npairs = ntiles * (ntiles + 1) / 2;
    const float4* bx = box4 + (size_t)bc * K_PRE;
    __shared__ float4 srb[64];
    int tid = threadIdx.x;
    int lane = tid & 63, w = tid >> 6;
    for (int p = blockIdx.x; p < npairs; p += IOU_BLK) {
        int ti = 0, acc = 0;
        while (acc + ti + 1 <= p) { acc += ti + 1; ++ti; }
        int tj = p - acc;
        __syncthreads();   // protect srb reuse across iterations
        if (tid < 64) srb[tid] = bx[ti * 64 + tid];
        __syncthreads();
        int cg = tj * 64 + lane;
        float4 cb = bx[cg];
        float ca = (cb.z - cb.x) * (cb.w - cb.y);
        u64* out = rowmask + (size_t)bc * TRI_WORDS + 64 * (ti * (ti + 1) / 2) + tj;
        #pragma unroll
        for (int r16 = 0; r16 < 16; ++r16) {
            int r = (w << 4) | r16;
            float4 rb = srb[r];
            float ra = (rb.z - rb.x) * (rb.w - rb.y);
            float iw = fminf(rb.z, cb.z) - fmaxf(rb.x, cb.x);
            float ih = fminf(rb.w, cb.w) - fmaxf(rb.y, cb.y);
            iw = fmaxf(iw, 0.f); ih = fmaxf(ih, 0.f);
            float inter = iw * ih;
            float iou = inter / (ra + ca - inter);
            int rg = ti * 64 + r;
            bool pr = (rg < n_cand) && (cg < n_cand) && ((ti != tj) || (lane < r)) &&
                      (iou > NMS_THR);
            u64 m = __ballot(pr);
            if (lane == 0) out[(size_t)r * (ti + 1)] = m;
        }
    }
}

// ---- D4: fused greedy + top-100 (proven R6/R8) ----
__global__ __launch_bounds__(1024) void k_fuse(const float* __restrict__ boxes,
                                               const float* __restrict__ rot,
                                               const float* __restrict__ trans,
                                               const int* __restrict__ cnt_g,
                                               const u64* __restrict__ sk_g,
                                               const u64* __restrict__ rowmask,
                                               float* __restrict__ out) {
    __shared__ u64 fk[1024];
    __shared__ int scnt[8];
    int tid = threadIdx.x;
    int lane = tid & 63, w = tid >> 6;
    int b = blockIdx.x;
    fk[tid] = 0ull;
    __syncthreads();
    if (w < 8) {
        int c = w;
        int bc = b * 8 + c;
        int cnt = cnt_g[bc];
        int n_cand = cnt < K_PRE ? cnt : K_PRE;
        int ntiles = (n_cand + 63) >> 6;
        const u64* tri = rowmask + (size_t)bc * TRI_WORDS;
        u64 kept_w[T_MAX];
        #pragma unroll
        for (int t = 0; t < T_MAX; ++t) kept_w[t] = 0ull;
        for (int t = 0; t < ntiles; ++t) {
            const u64* base = tri + 64 * (t * (t + 1) / 2) + (size_t)lane * (t + 1);
            u64 supbits = 0;
            #pragma unroll
            for (int ww = 0; ww < T_MAX - 1; ++ww)
                if (ww < t) supbits |= base[ww] & kept_w[ww];
            u64 rowm = base[t];
            int g = t * 64 + lane;
            bool el = (g < n_cand) && (supbits == 0ull);
            u64 alive = __ballot(el);
            u64 kb = 0;
            while (alive) {
                int j = __ffsll(alive) - 1;
                kb |= (1ull << j);
                u64 colj = __ballot(((rowm >> j) & 1ull) != 0);
                alive &= ~(colj | (1ull << j));
            }
            #pragma unroll
            for (int ww = 0; ww < T_MAX; ++ww)
                if (ww == t) kept_w[ww] = kb;
        }
        u64 lmask = (1ull << lane) - 1ull;
        int pre = 0;
        #pragma unroll
        for (int t = 0; t < T_MAX; ++t) {
            if (t < ntiles) {
                u64 kb = kept_w[t];
                if ((kb >> lane) & 1ull) {
                    int rank = pre + (int)__popcll(kb & lmask);
                    if (rank < KEEP_CAP) {
                        int i = t * 64 + lane;
                        u64 key = sk_g[(size_t)bc * K_PRE + i];
                        u32 sb = (u32)(key >> 32);
                        u32 n = (~(u32)key) & 0x1FFFFu;
                        int pos = c * K_PRE + i;
                        fk[c * KEEP_CAP + rank] =
                            ((u64)sb << 30) | ((u64)(8191 - pos) << 17) | (u64)n;
                    }
                }
                pre += (int)__popcll(kb);
            }
        }
        if (lane == 0) scnt[c] = pre < KEEP_CAP ? pre : KEEP_CAP;
    }
    __syncthreads();
    int c = tid >> 7, i = tid & 127;
    int cc = scnt[c];
    u64 key = fk[tid];
    int total = 0;
    #pragma unroll
    for (int r = 0; r < 8; ++r) total += scnt[r];
    if (i < cc) {
        int rank = i;
        #pragma unroll
        for (int r = 0; r < 8; ++r) {
            if (r == c) continue;
            int basei = r << 7;
            int lo;
            if (fk[basei + 127] > key) lo = 128;
            else {
                lo = 0;
                #pragma unroll
                for (int s = 64; s > 0; s >>= 1)
                    if (fk[basei + lo + s - 1] > key) lo += s;
            }
            rank += lo;
        }
        if (rank < MAX_DET) {
            u32 n = (u32)(key & 0x1FFFFu);
            int pos = 8191 - (int)((key >> 17) & 0x1FFFu);
            int cls = pos >> 10;
            float osc = __uint_as_float((u32)(key >> 30));
            const float* bp = boxes + ((size_t)b * NN + n) * 4;
            const float* rp = rot + ((size_t)b * NN + n) * 3;
            const float* tp = trans + ((size_t)b * NN + n) * 3;
            int base = b * MAX_DET + rank;
            out[base * 4 + 0] = bp[0];
            out[base * 4 + 1] = bp[1];
            out[base * 4 + 2] = bp[2];
            out[base * 4 + 3] = bp[3];
            out[BB * MAX_DET * 4 + base] = osc;
            out[BB * MAX_DET * 5 + base] = (float)cls;
            float* ro = out + BB * MAX_DET * 6;
            ro[base * 3 + 0] = rp[0];
            ro[base * 3 + 1] = rp[1];
            ro[base * 3 + 2] = rp[2];
            float* to = out + BB * MAX_DET * 6 + BB * MAX_DET * 3;
            to[base * 3 + 0] = tp[0];
            to[base * 3 + 1] = tp[1];
            to[base * 3 + 2] = tp[2];
        }
    }
    if (tid < MAX_DET && tid >= total) {
        int base = b * MAX_DET + tid;
        out[base * 4 + 0] = -1.f;
        out[base * 4 + 1] = -1.f;
        out[base * 4 + 2] = -1.f;
        out[base * 4 + 3] = -1.f;
        out[BB * MAX_DET * 4 + base] = -1.f;
        out[BB * MAX_DET * 5 + base] = -1.f;
        float* ro = out + BB * MAX_DET * 6;
        ro[base * 3 + 0] = -1.f;
        ro[base * 3 + 1] = -1.f;
        ro[base * 3 + 2] = -1.f;
        float* to = out + BB * MAX_DET * 6 + BB * MAX_DET * 3;
        to[base * 3 + 0] = -1.f;
        to[base * 3 + 1] = -1.f;
        to[base * 3 + 2] = -1.f;
    }
}

extern "C" void kernel_launch(void* const* d_in, const int* in_sizes, int n_in,
                              void* d_out, int out_size, void* d_ws, size_t ws_size,
                              hipStream_t stream) {
    const float* boxes = (const float*)d_in[0];
    const float* cls   = (const float*)d_in[1];
    const float* rot   = (const float*)d_in[2];
    const float* trans = (const float*)d_in[3];
    char* ws = (char*)d_ws;
    int* blkcnt    = (int*)ws;
    u64* cand_blk  = (u64*)(ws + 51200);
    int* cnt_g     = (int*)(ws + 3262464);
    u64* sk_g      = (u64*)(ws + 3262720);
    float4* box4   = (float4*)(ws + 3787008);
    u64* rowmask   = (u64*)(ws + 4835584);
    float* out = (float*)d_out;

    hipLaunchKernelGGL(k_filter, dim3(NBLK, BB), dim3(256), 0, stream,
                       cls, blkcnt, cand_blk);
    hipLaunchKernelGGL(k_sortB, dim3(64), dim3(256), 0, stream,
                       boxes, blkcnt, cand_blk, cnt_g, sk_g, box4);
    hipLaunchKernelGGL(k_iou, dim3(IOU_BLK, 64), dim3(256), 0, stream,
                       cnt_g, box4, rowmask);
    hipLaunchKernelGGL(k_fuse, dim3(BB), dim3(1024), 0, stream,
                       boxes, rot, trans, cnt_g, sk_g, rowmask, out);
}